// Round 1
// baseline (345.892 us; speedup 1.0000x reference)
//
#include <hip/hip_runtime.h>
#include <cmath>

#define N_NODES 100000
#define N_EDGES 3200000
#define IN_DIM 256
#define EMB 64
#define BATCH 4096
#define MWAVES 6250        // 100000 rows / 16 per wave (gemm)
#define NBUCK 782          // ceil(100000 / 128) row-buckets
#define BROWS 128          // rows per bucket
#define BSTRIDE 4608       // u64 slots per bucket (mean 4096 + 8 sigma), %8==0
#define PSTRIDE 5504       // LDS stage slots: BSTRIDE + 128*7 row-padding to %8
#define EPB 4096           // edges per passA block

typedef unsigned long long u64;
typedef unsigned int u32;
typedef unsigned short u16;
typedef __attribute__((ext_vector_type(8))) short bf16x8;
typedef __attribute__((ext_vector_type(4))) float f32x4;

// ---------------------------------------------------------------------------
// helpers
// ---------------------------------------------------------------------------
__device__ __forceinline__ float wave_sum(float v) {
#pragma unroll
    for (int m = 1; m < 64; m <<= 1) v += __shfl_xor(v, m, 64);
    return v;
}

__device__ __forceinline__ u16 f2bf_rne(float f) {
    u32 u = __float_as_uint(f);
    u32 r = ((u >> 16) & 1u) + 0x7FFFu;
    return (u16)((u + r) >> 16);
}

__device__ __forceinline__ float bf2f(u32 bits16) {
    return __uint_as_float(bits16 << 16);
}

// ---------------------------------------------------------------------------
// 1) xw = feats @ W via MFMA bf16. W staged in LDS fragment-major (32 KB).
//    All 16 A-tile float4 loads hoisted (one latency exposure per wave).
// ---------------------------------------------------------------------------
__global__ __launch_bounds__(256) void mfma_gemm_kernel(const float* __restrict__ feats,
                                                        const float* __restrict__ W,
                                                        u16* __restrict__ xwb) {
    __shared__ u16 wlds[32 * 64 * 8];   // 32 KB
    const int tid = threadIdx.x;
    for (int idx = tid; idx < 32 * 64; idx += 256) {
        const int f = idx >> 6, lane = idx & 63;
        const int kt = f >> 2, nt = f & 3;
        const int k0 = kt * 32 + (lane >> 4) * 8;
        const int n  = nt * 16 + (lane & 15);
        u32 buf[4];
#pragma unroll
        for (int jj = 0; jj < 4; ++jj) {
            u16 lo = f2bf_rne(W[(size_t)(k0 + 2 * jj) * EMB + n]);
            u16 hi = f2bf_rne(W[(size_t)(k0 + 2 * jj + 1) * EMB + n]);
            buf[jj] = (u32)lo | ((u32)hi << 16);
        }
        *(uint4*)&wlds[idx * 8] = *(uint4*)buf;
    }
    __syncthreads();

    const int wave = tid >> 6, lane = tid & 63;
    const int wid = blockIdx.x * 4 + wave;
    if (wid >= MWAVES) return;
    const int row0 = wid * 16;
    const int arow = row0 + (lane & 15);
    const int kbase = (lane >> 4) * 8;
    const float* fr = feats + (size_t)arow * IN_DIM + kbase;

    float4 av[16];
#pragma unroll
    for (int kt = 0; kt < 8; ++kt) {
        av[2 * kt]     = *(const float4*)(fr + kt * 32);
        av[2 * kt + 1] = *(const float4*)(fr + kt * 32 + 4);
    }

    f32x4 acc[4] = {};
    const u16* wl = &wlds[lane * 8];
#pragma unroll
    for (int kt = 0; kt < 8; ++kt) {
        float4 a0 = av[2 * kt], a1 = av[2 * kt + 1];
        u32 ab[4];
        ab[0] = (u32)f2bf_rne(a0.x) | ((u32)f2bf_rne(a0.y) << 16);
        ab[1] = (u32)f2bf_rne(a0.z) | ((u32)f2bf_rne(a0.w) << 16);
        ab[2] = (u32)f2bf_rne(a1.x) | ((u32)f2bf_rne(a1.y) << 16);
        ab[3] = (u32)f2bf_rne(a1.z) | ((u32)f2bf_rne(a1.w) << 16);
        bf16x8 afrag = *(bf16x8*)ab;
#pragma unroll
        for (int nt = 0; nt < 4; ++nt) {
            bf16x8 bfrag = *(const bf16x8*)&wl[(kt * 4 + nt) * 512];
            acc[nt] = __builtin_amdgcn_mfma_f32_16x16x32_bf16(afrag, bfrag, acc[nt], 0, 0, 0);
        }
    }
    const int rb = row0 + (lane >> 4) * 4;
    const int cb = lane & 15;
#pragma unroll
    for (int nt = 0; nt < 4; ++nt)
#pragma unroll
        for (int r = 0; r < 4; ++r)
            xwb[(size_t)(rb + r) * EMB + nt * 16 + cb] = f2bf_rne(acc[nt][r]);
}

// ---------------------------------------------------------------------------
// 2) passA: partition edges into NBUCK 128-row buckets (R6/R7-proven).
//    Entry packs (row:17 | col:17<<17 | val_bf16<<34).
// ---------------------------------------------------------------------------
__global__ __launch_bounds__(256) void passA_kernel(const int* __restrict__ erow,
                                                    const int* __restrict__ ecol,
                                                    const float* __restrict__ eval,
                                                    u32* __restrict__ gcursor,
                                                    u64* __restrict__ sorted) {
    __shared__ u64 stage[EPB];        // 32 KB
    __shared__ u32 hist[1024];
    __shared__ u32 offs[1024];
    __shared__ u32 cursor[1024];
    __shared__ u32 gbase[1024];
    __shared__ u32 partial[256];

    const int tid = threadIdx.x;
    const int e0 = blockIdx.x * EPB;
    const int total = min(EPB, N_EDGES - e0);

    for (int i = tid; i < 1024; i += 256) hist[i] = 0;
    __syncthreads();

    u64 ent[16];
    int eb[16];
#pragma unroll
    for (int j = 0; j < 16; ++j) {
        const int e = e0 + j * 256 + tid;
        if (e < N_EDGES) {
            const int r = erow[e];
            const int c = ecol[e];
            const u16 vb = f2bf_rne(eval[e]);
            ent[j] = (u64)(u32)r | ((u64)(u32)c << 17) | ((u64)vb << 34);
            eb[j] = r >> 7;
            atomicAdd(&hist[eb[j]], 1u);
        } else {
            eb[j] = -1;
        }
    }
    __syncthreads();

    u32 local[4], s = 0;
#pragma unroll
    for (int q = 0; q < 4; ++q) {
        local[q] = s;
        s += hist[4 * tid + q];
    }
    partial[tid] = s;
    __syncthreads();
    for (int off = 1; off < 256; off <<= 1) {
        u32 x = (tid >= off) ? partial[tid - off] : 0;
        __syncthreads();
        partial[tid] += x;
        __syncthreads();
    }
    const u32 base = partial[tid] - s;
#pragma unroll
    for (int q = 0; q < 4; ++q) {
        offs[4 * tid + q] = base + local[q];
        cursor[4 * tid + q] = base + local[q];
    }
    __syncthreads();

#pragma unroll
    for (int j = 0; j < 16; ++j) {
        if (eb[j] >= 0) {
            u32 pos = atomicAdd(&cursor[eb[j]], 1u);
            stage[pos] = ent[j];
        }
    }
    __syncthreads();

    for (int b = tid; b < 1024; b += 256) {
        const u32 cnt = cursor[b] - offs[b];
        gbase[b] = cnt ? atomicAdd(&gcursor[b], cnt) : 0;
    }
    __syncthreads();

    for (int i = tid; i < total; i += 256) {
        const u64 p = stage[i];
        const int b = (int)(p & 0x1FFFFu) >> 7;
        const u32 gpos = gbase[b] + ((u32)i - offs[b]);
        if (gpos < BSTRIDE) sorted[(size_t)b * BSTRIDE + gpos] = p;
    }
}

// ---------------------------------------------------------------------------
// 3) gather: one 512-thread block (8 waves) per 128-row bucket.
//    Entries read ONCE, coalesced, into registers (<=9/thread); LDS row-sort
//    PRE-TRANSFORMS each entry to {col_byte_off:u32, val_f32:u32} and pads
//    every row segment to a multiple of 8 edges (dummy col=0,val=0).
//    Sweep processes TWO edges per instruction: lanes 0-31 take edge j,
//    lanes 32-63 edge j+1; each lane loads a dword (2 bf16) of the xw row.
//    Per pair: 1 ds_read_b64 + 1 v_add + 1 global_load_dword + 2 unpack +
//    2 fmac (~2.5 VALU/edge vs ~9 before). Halves merged via shfl_xor(32).
//    3 blocks/CU (46 KB LDS) -> 768 resident of 782 total: ~no tail round.
// ---------------------------------------------------------------------------
__global__ __launch_bounds__(512, 6) void gather_kernel(const u16* __restrict__ xwb,
                                                        u64* __restrict__ sorted,
                                                        const u32* __restrict__ gcursor,
                                                        float* __restrict__ accumA) {
    __shared__ u64 stage[PSTRIDE];    // 44032 B: {col<<7, val_f32} pairs, row-sorted
    __shared__ u32 rhist[BROWS], roff[BROWS], rcur[BROWS], sc[BROWS];
    __shared__ float part[8];
    const int tid = threadIdx.x, wave = tid >> 6, lane = tid & 63;
    const int b = blockIdx.x;
    u64* gbase = sorted + (size_t)b * BSTRIDE;
    const int cnt = min((int)gcursor[b], BSTRIDE);

    if (tid < BROWS) rhist[tid] = 0;
    __syncthreads();

    // coalesced one-shot read into registers + histogram from registers
    u64 ent[9];                       // ceil(4608/512)
    int nloc = 0;
    for (int i = tid; i < cnt; i += 512) {
        u64 p = gbase[i];
        ent[nloc++] = p;
        atomicAdd(&rhist[(int)(p & 127u)], 1u);
    }
    __syncthreads();

    // exclusive scan of 128 row counts, padded to multiple of 8 per row
    if (tid < BROWS) sc[tid] = (rhist[tid] + 7u) & ~7u;
    __syncthreads();
    for (int off = 1; off < BROWS; off <<= 1) {
        u32 x = (tid < BROWS && tid >= off) ? sc[tid - off] : 0;
        __syncthreads();
        if (tid < BROWS) sc[tid] += x;
        __syncthreads();
    }
    if (tid < BROWS) {
        const u32 r0 = sc[tid] - ((rhist[tid] + 7u) & ~7u);
        roff[tid] = r0;
        rcur[tid] = r0;
    }
    __syncthreads();

    // scatter from registers into row-grouped LDS stage, pre-transformed:
    // lo32 = col byte offset (col*128), hi32 = val as f32 bits
    for (int j = 0; j < nloc; ++j) {
        const u64 p = ent[j];
        const u32 pos = atomicAdd(&rcur[(int)(p & 127u)], 1u);
        const u32 coff = (((u32)(p >> 17)) & 0x1FFFFu) << 7;
        const u32 v32  = (((u32)(p >> 34)) & 0xFFFFu) << 16;
        stage[pos] = (u64)coff | ((u64)v32 << 32);
    }
    __syncthreads();

    // pad each row segment to %8 with dummy entries (col 0, val 0.0f)
    if (tid < BROWS) {
        const int e = roff[tid] + rhist[tid];
        const int pe = roff[tid] + (int)((rhist[tid] + 7u) & ~7u);
        for (int k = e; k < pe; ++k) stage[k] = 0ull;
    }
    __syncthreads();

    // sweep: wave handles rows wave*16 .. wave*16+15; 2 edges per instr
    u16* embp = (u16*)gbase;          // entries dead (staged in LDS)
    const int lhalf = lane >> 5;      // 0: even edges, 1: odd edges
    const int loff = (lane & 31) * 4; // dword offset within the 128 B row
    const char* xwc = (const char*)xwb;
    float wd = 0.f;
    for (int rr = 0; rr < 16; ++rr) {
        const int r = wave * 16 + rr;
        const int n8 = (int)((rhist[r] + 7u) & ~7u);
        float acc0 = 0.f, acc1 = 0.f;
        const u64* sp = &stage[roff[r] + lhalf];
        for (int j = 0; j < n8; j += 8, sp += 8) {
            u64 cv0 = sp[0], cv1 = sp[2], cv2 = sp[4], cv3 = sp[6];
            u32 x0 = *(const u32*)(xwc + ((u32)cv0 + loff));
            u32 x1 = *(const u32*)(xwc + ((u32)cv1 + loff));
            u32 x2 = *(const u32*)(xwc + ((u32)cv2 + loff));
            u32 x3 = *(const u32*)(xwc + ((u32)cv3 + loff));
            float v0 = __uint_as_float((u32)(cv0 >> 32));
            float v1 = __uint_as_float((u32)(cv1 >> 32));
            float v2 = __uint_as_float((u32)(cv2 >> 32));
            float v3 = __uint_as_float((u32)(cv3 >> 32));
            acc0 += v0 * __uint_as_float(x0 << 16);
            acc1 += v0 * __uint_as_float(x0 & 0xFFFF0000u);
            acc0 += v1 * __uint_as_float(x1 << 16);
            acc1 += v1 * __uint_as_float(x1 & 0xFFFF0000u);
            acc0 += v2 * __uint_as_float(x2 << 16);
            acc1 += v2 * __uint_as_float(x2 & 0xFFFF0000u);
            acc0 += v3 * __uint_as_float(x3 << 16);
            acc1 += v3 * __uint_as_float(x3 & 0xFFFF0000u);
        }
        // merge the two half-wave edge subsets (same element positions)
        acc0 += __shfl_xor(acc0, 32, 64);
        acc1 += __shfl_xor(acc1, 32, 64);
        const float t0 = tanhf(acc0);
        const float t1 = tanhf(acc1);
        float sq = t0 * t0 + t1 * t1;
#pragma unroll
        for (int m = 1; m < 32; m <<= 1) sq += __shfl_xor(sq, m, 64);
        const float rn = rsqrtf(fmaxf(sq, 1e-12f));
        if (lhalf == 0 && b * BROWS + r < N_NODES) {
            const u32 o = (u32)f2bf_rne(t0 * rn) | ((u32)f2bf_rne(t1 * rn) << 16);
            *(u32*)&embp[r * EMB + (lane & 31) * 2] = o;
        }
        wd += sq / fmaxf(sq, 1e-12f);   // 1 per non-empty row, 0 for empty
    }
    if (lane == 0) part[wave] = wd;
    __syncthreads();
    if (tid == 0) {
        float v = 0.f;
#pragma unroll
        for (int w = 0; w < 8; ++w) v += part[w];
        unsafeAtomicAdd(&accumA[b & 255], v);
    }
}

// ---------------------------------------------------------------------------
// 4) BPR: pure emb lookup. One wave per sample.
// ---------------------------------------------------------------------------
__device__ __forceinline__ float emb_ld(const u64* __restrict__ sorted, int row, int lane) {
    const u16* rp = (const u16*)(sorted + (size_t)(row >> 7) * BSTRIDE) + (row & 127) * EMB;
    return bf2f(rp[lane]);
}

__global__ __launch_bounds__(256) void bpr_kernel(const u64* __restrict__ sorted,
                                                  const int* __restrict__ idx1,
                                                  const int* __restrict__ idx2,
                                                  const int* __restrict__ nidx,
                                                  float* __restrict__ accumB) {
    const int wave = threadIdx.x >> 6, lane = threadIdx.x & 63;
    const int i = blockIdx.x * 4 + wave;
    float o1 = emb_ld(sorted, idx1[i], lane);
    float o2 = emb_ld(sorted, idx2[i], lane);
    float on = emb_ld(sorted, nidx[i], lane);
    float yui = wave_sum(o1 * o2);
    float yuj = wave_sum(o1 * on);
    if (lane == 0) {
        float x = yui - yuj;
        float li = (x > 0.f) ? log1pf(expf(-x)) : (-x + log1pf(expf(x)));
        unsafeAtomicAdd(&accumB[i & 255], li);
    }
}

// ---------------------------------------------------------------------------
// 5) finalize
// ---------------------------------------------------------------------------
__global__ __launch_bounds__(64) void finalize_kernel(const float* __restrict__ accumA,
                                                      const float* __restrict__ accumB,
                                                      float* __restrict__ out) {
    const int t = threadIdx.x;
    float wd = 0.f, bp = 0.f;
#pragma unroll
    for (int k = 0; k < 4; ++k) {
        wd += accumA[t + 64 * k];
        bp += accumB[t + 64 * k];
    }
    wd = wave_sum(wd);
    bp = wave_sum(bp);
    if (t == 0) out[0] = (bp + 1e-4f * 0.5f * wd) / (float)BATCH;
}

extern "C" void kernel_launch(void* const* d_in, const int* in_sizes, int n_in,
                              void* d_out, int out_size, void* d_ws, size_t ws_size,
                              hipStream_t stream) {
    const float* feats = (const float*)d_in[0];
    const float* W     = (const float*)d_in[1];
    const int*   erow  = (const int*)d_in[2];
    const int*   ecol  = (const int*)d_in[3];
    const float* eval  = (const float*)d_in[4];
    const int*   idx1  = (const int*)d_in[5];
    const int*   idx2  = (const int*)d_in[6];
    const int*   nidx  = (const int*)d_in[7];
    float* out = (float*)d_out;

    // workspace layout (~41.7 MB)
    u16*   xwb     = (u16*)d_ws;                               // 12.8 MB
    u64*   sorted  = (u64*)(xwb + (size_t)N_NODES * EMB);      // 782*4608*8 = 28.8 MB
    u32*   gcursor = (u32*)(sorted + (size_t)NBUCK * BSTRIDE); // 1024
    float* accumA  = (float*)(gcursor + 1024);                 // 256
    float* accumB  = accumA + 256;                             // 256

    hipMemsetAsync(gcursor, 0, (1024 + 512) * sizeof(u32), stream);

    mfma_gemm_kernel<<<(MWAVES + 3) / 4, 256, 0, stream>>>(feats, W, xwb);
    passA_kernel<<<(N_EDGES + EPB - 1) / EPB, 256, 0, stream>>>(erow, ecol, eval, gcursor, sorted);
    gather_kernel<<<NBUCK, 512, 0, stream>>>(xwb, sorted, gcursor, accumA);
    bpr_kernel<<<BATCH / 4, 256, 0, stream>>>(sorted, idx1, idx2, nidx, accumB);
    finalize_kernel<<<1, 64, 0, stream>>>(accumA, accumB, out);
}

// Round 3
// 314.361 us; speedup vs baseline: 1.1003x; 1.1003x over previous
//
#include <hip/hip_runtime.h>
#include <cmath>

#define N_NODES 100000
#define N_EDGES 3200000
#define IN_DIM 256
#define EMB 64
#define BATCH 4096
#define MWAVES 6250        // 100000 rows / 16 per wave (gemm)
#define NBUCK 782          // ceil(100000 / 128) row-buckets
#define BROWS 128          // rows per bucket
#define BSTRIDE 4608       // u64 slots per bucket (mean 4096 + 8 sigma), %8==0
#define PSTRIDE 5504       // LDS stage slots: BSTRIDE + 128*7 row-padding to %8
#define EPB 4096           // edges per passA block

typedef unsigned long long u64;
typedef unsigned int u32;
typedef unsigned short u16;
typedef __attribute__((ext_vector_type(8))) short bf16x8;
typedef __attribute__((ext_vector_type(4))) float f32x4;

// ---------------------------------------------------------------------------
// helpers
// ---------------------------------------------------------------------------
__device__ __forceinline__ float wave_sum(float v) {
#pragma unroll
    for (int m = 1; m < 64; m <<= 1) v += __shfl_xor(v, m, 64);
    return v;
}

__device__ __forceinline__ u16 f2bf_rne(float f) {
    u32 u = __float_as_uint(f);
    u32 r = ((u >> 16) & 1u) + 0x7FFFu;
    return (u16)((u + r) >> 16);
}

__device__ __forceinline__ float bf2f(u32 bits16) {
    return __uint_as_float(bits16 << 16);
}

// ---------------------------------------------------------------------------
// 1) xw = feats @ W via MFMA bf16. W staged in LDS fragment-major (32 KB).
// ---------------------------------------------------------------------------
__global__ __launch_bounds__(256) void mfma_gemm_kernel(const float* __restrict__ feats,
                                                        const float* __restrict__ W,
                                                        u16* __restrict__ xwb) {
    __shared__ u16 wlds[32 * 64 * 8];   // 32 KB
    const int tid = threadIdx.x;
    for (int idx = tid; idx < 32 * 64; idx += 256) {
        const int f = idx >> 6, lane = idx & 63;
        const int kt = f >> 2, nt = f & 3;
        const int k0 = kt * 32 + (lane >> 4) * 8;
        const int n  = nt * 16 + (lane & 15);
        u32 buf[4];
#pragma unroll
        for (int jj = 0; jj < 4; ++jj) {
            u16 lo = f2bf_rne(W[(size_t)(k0 + 2 * jj) * EMB + n]);
            u16 hi = f2bf_rne(W[(size_t)(k0 + 2 * jj + 1) * EMB + n]);
            buf[jj] = (u32)lo | ((u32)hi << 16);
        }
        *(uint4*)&wlds[idx * 8] = *(uint4*)buf;
    }
    __syncthreads();

    const int wave = tid >> 6, lane = tid & 63;
    const int wid = blockIdx.x * 4 + wave;
    if (wid >= MWAVES) return;
    const int row0 = wid * 16;
    const int arow = row0 + (lane & 15);
    const int kbase = (lane >> 4) * 8;
    const float* fr = feats + (size_t)arow * IN_DIM + kbase;

    float4 av[16];
#pragma unroll
    for (int kt = 0; kt < 8; ++kt) {
        av[2 * kt]     = *(const float4*)(fr + kt * 32);
        av[2 * kt + 1] = *(const float4*)(fr + kt * 32 + 4);
    }

    f32x4 acc[4] = {};
    const u16* wl = &wlds[lane * 8];
#pragma unroll
    for (int kt = 0; kt < 8; ++kt) {
        float4 a0 = av[2 * kt], a1 = av[2 * kt + 1];
        u32 ab[4];
        ab[0] = (u32)f2bf_rne(a0.x) | ((u32)f2bf_rne(a0.y) << 16);
        ab[1] = (u32)f2bf_rne(a0.z) | ((u32)f2bf_rne(a0.w) << 16);
        ab[2] = (u32)f2bf_rne(a1.x) | ((u32)f2bf_rne(a1.y) << 16);
        ab[3] = (u32)f2bf_rne(a1.z) | ((u32)f2bf_rne(a1.w) << 16);
        bf16x8 afrag = *(bf16x8*)ab;
#pragma unroll
        for (int nt = 0; nt < 4; ++nt) {
            bf16x8 bfrag = *(const bf16x8*)&wl[(kt * 4 + nt) * 512];
            acc[nt] = __builtin_amdgcn_mfma_f32_16x16x32_bf16(afrag, bfrag, acc[nt], 0, 0, 0);
        }
    }
    const int rb = row0 + (lane >> 4) * 4;
    const int cb = lane & 15;
#pragma unroll
    for (int nt = 0; nt < 4; ++nt)
#pragma unroll
        for (int r = 0; r < 4; ++r)
            xwb[(size_t)(rb + r) * EMB + nt * 16 + cb] = f2bf_rne(acc[nt][r]);
}

// ---------------------------------------------------------------------------
// 2) passA: partition edges into NBUCK 128-row buckets.
//    Entry packs (row:17 | col:17<<17 | val_bf16<<34).
// ---------------------------------------------------------------------------
__global__ __launch_bounds__(256) void passA_kernel(const int* __restrict__ erow,
                                                    const int* __restrict__ ecol,
                                                    const float* __restrict__ eval,
                                                    u32* __restrict__ gcursor,
                                                    u64* __restrict__ sorted) {
    __shared__ u64 stage[EPB];        // 32 KB
    __shared__ u32 hist[1024];
    __shared__ u32 offs[1024];
    __shared__ u32 cursor[1024];
    __shared__ u32 gbase[1024];
    __shared__ u32 partial[256];

    const int tid = threadIdx.x;
    const int e0 = blockIdx.x * EPB;
    const int total = min(EPB, N_EDGES - e0);

    for (int i = tid; i < 1024; i += 256) hist[i] = 0;
    __syncthreads();

    u64 ent[16];
    int eb[16];
#pragma unroll
    for (int j = 0; j < 16; ++j) {
        const int e = e0 + j * 256 + tid;
        if (e < N_EDGES) {
            const int r = erow[e];
            const int c = ecol[e];
            const u16 vb = f2bf_rne(eval[e]);
            ent[j] = (u64)(u32)r | ((u64)(u32)c << 17) | ((u64)vb << 34);
            eb[j] = r >> 7;
            atomicAdd(&hist[eb[j]], 1u);
        } else {
            eb[j] = -1;
        }
    }
    __syncthreads();

    u32 local[4], s = 0;
#pragma unroll
    for (int q = 0; q < 4; ++q) {
        local[q] = s;
        s += hist[4 * tid + q];
    }
    partial[tid] = s;
    __syncthreads();
    for (int off = 1; off < 256; off <<= 1) {
        u32 x = (tid >= off) ? partial[tid - off] : 0;
        __syncthreads();
        partial[tid] += x;
        __syncthreads();
    }
    const u32 base = partial[tid] - s;
#pragma unroll
    for (int q = 0; q < 4; ++q) {
        offs[4 * tid + q] = base + local[q];
        cursor[4 * tid + q] = base + local[q];
    }
    __syncthreads();

#pragma unroll
    for (int j = 0; j < 16; ++j) {
        if (eb[j] >= 0) {
            u32 pos = atomicAdd(&cursor[eb[j]], 1u);
            stage[pos] = ent[j];
        }
    }
    __syncthreads();

    for (int b = tid; b < 1024; b += 256) {
        const u32 cnt = cursor[b] - offs[b];
        gbase[b] = cnt ? atomicAdd(&gcursor[b], cnt) : 0;
    }
    __syncthreads();

    for (int i = tid; i < total; i += 256) {
        const u64 p = stage[i];
        const int b = (int)(p & 0x1FFFFu) >> 7;
        const u32 gpos = gbase[b] + ((u32)i - offs[b]);
        if (gpos < BSTRIDE) sorted[(size_t)b * BSTRIDE + gpos] = p;
    }
}

// ---------------------------------------------------------------------------
// 3) gather: one 512-thread block (8 waves) per 128-row bucket.
//    LDS stage split into u32 coff[] + u16 val[] (6 B/entry -> 35.1 KB total,
//    LDS allows 4 blocks/CU = 32 waves/CU; 1024 resident slots >= 782 blocks
//    -> single dispatch round). launch_bounds min kept at 4 waves/EU so the
//    allocator is NOT forced under 64 VGPR (no scratch spill in hot loop).
//    Sweep: eighth-wave groups. 8 lanes per edge, each lane loads dwordx4
//    (16 B of the 128 B xw row) -> 8 edges per load instruction (1 KB/instr),
//    unrolled x2 (2 KB in flight/wave). Per 8 edges: 2 ds_read + 1 VMEM +
//    16 unpack/fma. Cross-group merge via 3-stage recursive-halving
//    reduce-scatter (7 shfl) leaving ONE element per lane -> 1 tanh/lane,
//    single u16 store per lane per row.
// ---------------------------------------------------------------------------
__global__ __launch_bounds__(512, 4) void gather_kernel(const u16* __restrict__ xwb,
                                                        u64* __restrict__ sorted,
                                                        const u32* __restrict__ gcursor,
                                                        float* __restrict__ accumA) {
    __shared__ u32 scoff[PSTRIDE];    // 22016 B: col byte offsets (col*128)
    __shared__ u16 sval[PSTRIDE];     // 11008 B: edge vals (bf16 bits)
    __shared__ u32 rhist[BROWS], roff[BROWS], rcur[BROWS], sc[BROWS];
    __shared__ float part[8];
    const int tid = threadIdx.x, wave = tid >> 6, lane = tid & 63;
    const int b = blockIdx.x;
    u64* gbase = sorted + (size_t)b * BSTRIDE;
    const int cnt = min((int)gcursor[b], BSTRIDE);

    if (tid < BROWS) rhist[tid] = 0;
    __syncthreads();

    // coalesced one-shot read into registers + histogram from registers
    u64 ent[9];                       // ceil(4608/512)
    int nloc = 0;
    for (int i = tid; i < cnt; i += 512) {
        u64 p = gbase[i];
        ent[nloc++] = p;
        atomicAdd(&rhist[(int)(p & 127u)], 1u);
    }
    __syncthreads();

    // exclusive scan of 128 row counts, padded to multiple of 8 per row
    if (tid < BROWS) sc[tid] = (rhist[tid] + 7u) & ~7u;
    __syncthreads();
    for (int off = 1; off < BROWS; off <<= 1) {
        u32 x = (tid < BROWS && tid >= off) ? sc[tid - off] : 0;
        __syncthreads();
        if (tid < BROWS) sc[tid] += x;
        __syncthreads();
    }
    if (tid < BROWS) {
        const u32 r0 = sc[tid] - ((rhist[tid] + 7u) & ~7u);
        roff[tid] = r0;
        rcur[tid] = r0;
    }
    __syncthreads();

    // scatter from registers into row-grouped LDS stage, pre-transformed
    for (int j = 0; j < nloc; ++j) {
        const u64 p = ent[j];
        const u32 pos = atomicAdd(&rcur[(int)(p & 127u)], 1u);
        scoff[pos] = (((u32)(p >> 17)) & 0x1FFFFu) << 7;
        sval[pos]  = (u16)(p >> 34);
    }
    __syncthreads();

    // pad each row segment to %8 with dummy entries (col 0, val 0.0f)
    if (tid < BROWS) {
        const int e = roff[tid] + rhist[tid];
        const int pe = roff[tid] + (int)((rhist[tid] + 7u) & ~7u);
        for (int k = e; k < pe; ++k) { scoff[k] = 0u; sval[k] = 0; }
    }
    __syncthreads();

    // sweep: wave handles rows wave*16 .. wave*16+15
    u16* embp = (u16*)gbase;          // entries dead (staged in LDS)
    const int g = lane >> 3;          // edge slot within group of 8
    const int eoff = (lane & 7) * 16; // byte offset of this lane's 16 B chunk
    const int g0 = g & 1, g1 = (g >> 1) & 1, g2 = (g >> 2) & 1;
    const int el = (lane & 7) * 8 + 4 * g0 + 2 * g1 + g2; // final element
    const char* xwc = (const char*)xwb;
    float wd = 0.f;

#define FMA8(X, V)                                         \
    acc[0] += (V) * __uint_as_float((X).x << 16);          \
    acc[1] += (V) * __uint_as_float((X).x & 0xFFFF0000u);  \
    acc[2] += (V) * __uint_as_float((X).y << 16);          \
    acc[3] += (V) * __uint_as_float((X).y & 0xFFFF0000u);  \
    acc[4] += (V) * __uint_as_float((X).z << 16);          \
    acc[5] += (V) * __uint_as_float((X).z & 0xFFFF0000u);  \
    acc[6] += (V) * __uint_as_float((X).w << 16);          \
    acc[7] += (V) * __uint_as_float((X).w & 0xFFFF0000u);

    for (int rr = 0; rr < 16; ++rr) {
        const int r = wave * 16 + rr;
        const int n8 = (int)((rhist[r] + 7u) & ~7u);
        const int base = (int)roff[r];
        float acc[8] = {0.f, 0.f, 0.f, 0.f, 0.f, 0.f, 0.f, 0.f};

        int j = 0;
        for (; j + 16 <= n8; j += 16) {
            const int i0 = base + j + g;
            const u32 c0 = scoff[i0];
            const u32 c1 = scoff[i0 + 8];
            const float v0 = bf2f(sval[i0]);
            const float v1 = bf2f(sval[i0 + 8]);
            const uint4 x0 = *(const uint4*)(xwc + (c0 + eoff));
            const uint4 x1 = *(const uint4*)(xwc + (c1 + eoff));
            FMA8(x0, v0)
            FMA8(x1, v1)
        }
        if (j < n8) {
            const int i0 = base + j + g;
            const u32 c0 = scoff[i0];
            const float v0 = bf2f(sval[i0]);
            const uint4 x0 = *(const uint4*)(xwc + (c0 + eoff));
            FMA8(x0, v0)
        }

        // 3-stage reduce-scatter across groups: lane ends with element el
        float k4[4];
#pragma unroll
        for (int i = 0; i < 4; ++i) {
            const float snd = g0 ? acc[i] : acc[i + 4];
            const float kp  = g0 ? acc[i + 4] : acc[i];
            k4[i] = kp + __shfl_xor(snd, 8, 64);
        }
        float k2[2];
#pragma unroll
        for (int i = 0; i < 2; ++i) {
            const float snd = g1 ? k4[i] : k4[i + 2];
            const float kp  = g1 ? k4[i + 2] : k4[i];
            k2[i] = kp + __shfl_xor(snd, 16, 64);
        }
        const float snd = g2 ? k2[0] : k2[1];
        const float kp  = g2 ? k2[1] : k2[0];
        const float s = kp + __shfl_xor(snd, 32, 64);

        const float t = tanhf(s);
        const float sq = wave_sum(t * t);
        const float rn = rsqrtf(fmaxf(sq, 1e-12f));
        if (b * BROWS + r < N_NODES)
            embp[r * EMB + el] = f2bf_rne(t * rn);
        wd += sq / fmaxf(sq, 1e-12f);   // 1 per non-empty row, 0 for empty
    }
#undef FMA8
    if (lane == 0) part[wave] = wd;
    __syncthreads();
    if (tid == 0) {
        float v = 0.f;
#pragma unroll
        for (int w = 0; w < 8; ++w) v += part[w];
        unsafeAtomicAdd(&accumA[b & 255], v);
    }
}

// ---------------------------------------------------------------------------
// 4) BPR: pure emb lookup. One wave per sample.
// ---------------------------------------------------------------------------
__device__ __forceinline__ float emb_ld(const u64* __restrict__ sorted, int row, int lane) {
    const u16* rp = (const u16*)(sorted + (size_t)(row >> 7) * BSTRIDE) + (row & 127) * EMB;
    return bf2f(rp[lane]);
}

__global__ __launch_bounds__(256) void bpr_kernel(const u64* __restrict__ sorted,
                                                  const int* __restrict__ idx1,
                                                  const int* __restrict__ idx2,
                                                  const int* __restrict__ nidx,
                                                  float* __restrict__ accumB) {
    const int wave = threadIdx.x >> 6, lane = threadIdx.x & 63;
    const int i = blockIdx.x * 4 + wave;
    float o1 = emb_ld(sorted, idx1[i], lane);
    float o2 = emb_ld(sorted, idx2[i], lane);
    float on = emb_ld(sorted, nidx[i], lane);
    float yui = wave_sum(o1 * o2);
    float yuj = wave_sum(o1 * on);
    if (lane == 0) {
        float x = yui - yuj;
        float li = (x > 0.f) ? log1pf(expf(-x)) : (-x + log1pf(expf(x)));
        unsafeAtomicAdd(&accumB[i & 255], li);
    }
}

// ---------------------------------------------------------------------------
// 5) finalize
// ---------------------------------------------------------------------------
__global__ __launch_bounds__(64) void finalize_kernel(const float* __restrict__ accumA,
                                                      const float* __restrict__ accumB,
                                                      float* __restrict__ out) {
    const int t = threadIdx.x;
    float wd = 0.f, bp = 0.f;
#pragma unroll
    for (int k = 0; k < 4; ++k) {
        wd += accumA[t + 64 * k];
        bp += accumB[t + 64 * k];
    }
    wd = wave_sum(wd);
    bp = wave_sum(bp);
    if (t == 0) out[0] = (bp + 1e-4f * 0.5f * wd) / (float)BATCH;
}

extern "C" void kernel_launch(void* const* d_in, const int* in_sizes, int n_in,
                              void* d_out, int out_size, void* d_ws, size_t ws_size,
                              hipStream_t stream) {
    const float* feats = (const float*)d_in[0];
    const float* W     = (const float*)d_in[1];
    const int*   erow  = (const int*)d_in[2];
    const int*   ecol  = (const int*)d_in[3];
    const float* eval  = (const float*)d_in[4];
    const int*   idx1  = (const int*)d_in[5];
    const int*   idx2  = (const int*)d_in[6];
    const int*   nidx  = (const int*)d_in[7];
    float* out = (float*)d_out;

    // workspace layout (~41.7 MB)
    u16*   xwb     = (u16*)d_ws;                               // 12.8 MB
    u64*   sorted  = (u64*)(xwb + (size_t)N_NODES * EMB);      // 782*4608*8 = 28.8 MB
    u32*   gcursor = (u32*)(sorted + (size_t)NBUCK * BSTRIDE); // 1024
    float* accumA  = (float*)(gcursor + 1024);                 // 256
    float* accumB  = accumA + 256;                             // 256

    hipMemsetAsync(gcursor, 0, (1024 + 512) * sizeof(u32), stream);

    mfma_gemm_kernel<<<(MWAVES + 3) / 4, 256, 0, stream>>>(feats, W, xwb);
    passA_kernel<<<(N_EDGES + EPB - 1) / EPB, 256, 0, stream>>>(erow, ecol, eval, gcursor, sorted);
    gather_kernel<<<NBUCK, 512, 0, stream>>>(xwb, sorted, gcursor, accumA);
    bpr_kernel<<<BATCH / 4, 256, 0, stream>>>(sorted, idx1, idx2, nidx, accumB);
    finalize_kernel<<<1, 64, 0, stream>>>(accumA, accumB, out);
}

// Round 4
// 280.062 us; speedup vs baseline: 1.2351x; 1.1225x over previous
//
#include <hip/hip_runtime.h>
#include <cmath>

#define N_NODES 100000
#define N_EDGES 3200000
#define IN_DIM 256
#define EMB 64
#define BATCH 4096
#define MWAVES 6250        // 100000 rows / 16 per wave (gemm)
#define NBUCK 782          // ceil(100000 / 128) row-buckets
#define BROWS 128          // rows per bucket
#define BSTRIDE 4608       // u64 slots per bucket (mean 4096 + 8 sigma), %8==0
#define PSTRIDE 5504       // gather LDS stage slots: BSTRIDE + 128*7 row-padding
#define EPB 12544          // edges per passA block -> exactly 256 blocks
#define NPA 256            // ceil(N_EDGES / EPB) = 256 (1 block/CU, 1 round)

typedef unsigned long long u64;
typedef unsigned int u32;
typedef unsigned short u16;
typedef __attribute__((ext_vector_type(8))) short bf16x8;
typedef __attribute__((ext_vector_type(4))) float f32x4;

// ---------------------------------------------------------------------------
// helpers
// ---------------------------------------------------------------------------
__device__ __forceinline__ float wave_sum(float v) {
#pragma unroll
    for (int m = 1; m < 64; m <<= 1) v += __shfl_xor(v, m, 64);
    return v;
}

__device__ __forceinline__ u16 f2bf_rne(float f) {
    u32 u = __float_as_uint(f);
    u32 r = ((u >> 16) & 1u) + 0x7FFFu;
    return (u16)((u + r) >> 16);
}

__device__ __forceinline__ float bf2f(u32 bits16) {
    return __uint_as_float(bits16 << 16);
}

// ---------------------------------------------------------------------------
// 0) wpack: one-time W (f32) -> bf16 fragment-major pack (32 KB global).
//    Removes ~340 VALU instrs of f2bf prologue from EVERY gemm block.
// ---------------------------------------------------------------------------
__global__ __launch_bounds__(256) void wpack_kernel(const float* __restrict__ W,
                                                    u16* __restrict__ wpack) {
    const int idx = blockIdx.x * 256 + threadIdx.x;   // 0..2047
    const int f = idx >> 6, lane = idx & 63;
    const int kt = f >> 2, nt = f & 3;
    const int k0 = kt * 32 + (lane >> 4) * 8;
    const int n  = nt * 16 + (lane & 15);
    u32 buf[4];
#pragma unroll
    for (int jj = 0; jj < 4; ++jj) {
        u16 lo = f2bf_rne(W[(size_t)(k0 + 2 * jj) * EMB + n]);
        u16 hi = f2bf_rne(W[(size_t)(k0 + 2 * jj + 1) * EMB + n]);
        buf[jj] = (u32)lo | ((u32)hi << 16);
    }
    *(uint4*)&wpack[idx * 8] = *(uint4*)buf;
}

// ---------------------------------------------------------------------------
// 1) xw = feats @ W via MFMA bf16. W staged in LDS from pre-packed global
//    (pure uint4 copy, no conversion).
// ---------------------------------------------------------------------------
__global__ __launch_bounds__(256) void mfma_gemm_kernel(const float* __restrict__ feats,
                                                        const u16* __restrict__ wpack,
                                                        u16* __restrict__ xwb) {
    __shared__ u16 wlds[32 * 64 * 8];   // 32 KB
    const int tid = threadIdx.x;
    for (int idx = tid; idx < 32 * 64; idx += 256)
        *(uint4*)&wlds[idx * 8] = *(const uint4*)&wpack[idx * 8];
    __syncthreads();

    const int wave = tid >> 6, lane = tid & 63;
    const int wid = blockIdx.x * 4 + wave;
    if (wid >= MWAVES) return;
    const int row0 = wid * 16;
    const int arow = row0 + (lane & 15);
    const int kbase = (lane >> 4) * 8;
    const float* fr = feats + (size_t)arow * IN_DIM + kbase;

    float4 av[16];
#pragma unroll
    for (int kt = 0; kt < 8; ++kt) {
        av[2 * kt]     = *(const float4*)(fr + kt * 32);
        av[2 * kt + 1] = *(const float4*)(fr + kt * 32 + 4);
    }

    f32x4 acc[4] = {};
    const u16* wl = &wlds[lane * 8];
#pragma unroll
    for (int kt = 0; kt < 8; ++kt) {
        float4 a0 = av[2 * kt], a1 = av[2 * kt + 1];
        u32 ab[4];
        ab[0] = (u32)f2bf_rne(a0.x) | ((u32)f2bf_rne(a0.y) << 16);
        ab[1] = (u32)f2bf_rne(a0.z) | ((u32)f2bf_rne(a0.w) << 16);
        ab[2] = (u32)f2bf_rne(a1.x) | ((u32)f2bf_rne(a1.y) << 16);
        ab[3] = (u32)f2bf_rne(a1.z) | ((u32)f2bf_rne(a1.w) << 16);
        bf16x8 afrag = *(bf16x8*)ab;
#pragma unroll
        for (int nt = 0; nt < 4; ++nt) {
            bf16x8 bfrag = *(const bf16x8*)&wl[(kt * 4 + nt) * 512];
            acc[nt] = __builtin_amdgcn_mfma_f32_16x16x32_bf16(afrag, bfrag, acc[nt], 0, 0, 0);
        }
    }
    const int rb = row0 + (lane >> 4) * 4;
    const int cb = lane & 15;
#pragma unroll
    for (int nt = 0; nt < 4; ++nt)
#pragma unroll
        for (int r = 0; r < 4; ++r)
            xwb[(size_t)(rb + r) * EMB + nt * 16 + cb] = f2bf_rne(acc[nt][r]);
}

// ---------------------------------------------------------------------------
// 2) passA: partition edges into NBUCK 128-row buckets.
//    Entry packs (row:17 | col:17<<17 | val_bf16<<34).
//    v2: 1024 threads, EPB 12544 -> EXACTLY 256 blocks (1/CU, one balanced
//    round, 16 waves/CU). Global reservation atomics 800K -> 262K (-67%);
//    per-bucket write segments ~4 -> ~12 edges (98 B bursts, less write
//    amplification). LDS: 98 KB stage + 16 KB tables = 114.7 KB (gfx950
//    allows up to 160 KB static).
// ---------------------------------------------------------------------------
__global__ __launch_bounds__(1024, 4) void passA_kernel(const int* __restrict__ erow,
                                                        const int* __restrict__ ecol,
                                                        const float* __restrict__ eval,
                                                        u32* __restrict__ gcursor,
                                                        u64* __restrict__ sorted) {
    __shared__ u64 stage[EPB];        // 100352 B
    __shared__ u32 hist[1024];
    __shared__ u32 harr[1024];        // scan array -> becomes offs
    __shared__ u32 cursor[1024];
    __shared__ u32 gbase[1024];

    const int tid = threadIdx.x;
    const int e0 = blockIdx.x * EPB;
    const int total = min(EPB, N_EDGES - e0);

    hist[tid] = 0;
    __syncthreads();

    // read up to 13 edges/thread into registers + LDS histogram
    u64 ent[13];
#pragma unroll
    for (int j = 0; j < 13; ++j) {
        const int le = j * 1024 + tid;
        if (le < total) {
            const int e = e0 + le;
            const int r = erow[e];
            const int c = ecol[e];
            const u16 vb = f2bf_rne(eval[e]);
            ent[j] = (u64)(u32)r | ((u64)(u32)c << 17) | ((u64)vb << 34);
            atomicAdd(&hist[r >> 7], 1u);
        }
    }
    __syncthreads();

    // Hillis-Steele inclusive scan over 1024 buckets (thread == bucket)
    const u32 h = hist[tid];
    harr[tid] = h;
    __syncthreads();
    for (int off = 1; off < 1024; off <<= 1) {
        u32 x = (tid >= off) ? harr[tid - off] : 0;
        __syncthreads();
        harr[tid] += x;
        __syncthreads();
    }
    const u32 myoff = harr[tid] - h;
    __syncthreads();
    harr[tid] = myoff;                // harr now = exclusive offsets
    cursor[tid] = myoff;
    gbase[tid] = h ? atomicAdd(&gcursor[tid], h) : 0u;
    __syncthreads();

    // scatter from registers into bucket-grouped LDS stage
#pragma unroll
    for (int j = 0; j < 13; ++j) {
        const int le = j * 1024 + tid;
        if (le < total) {
            const u64 p = ent[j];
            const u32 pos = atomicAdd(&cursor[(int)(p & 0x1FFFFu) >> 7], 1u);
            stage[pos] = p;
        }
    }
    __syncthreads();

    // grouped coalesced write-out (segments ~12 edges = 98 B bursts)
    for (int i = tid; i < total; i += 1024) {
        const u64 p = stage[i];
        const int bk = (int)(p & 0x1FFFFu) >> 7;
        const u32 gpos = gbase[bk] + ((u32)i - harr[bk]);
        if (gpos < BSTRIDE) sorted[(size_t)bk * BSTRIDE + gpos] = p;
    }
}

// ---------------------------------------------------------------------------
// 3) gather: one 512-thread block (8 waves) per 128-row bucket. (unchanged)
//    Eighth-wave groups: 8 lanes per edge, each lane loads dwordx4 of the
//    128 B xw row -> 8 edges per load instruction, x2 unroll. 3-stage
//    reduce-scatter leaves one element per lane -> 1 tanh + 1 store/lane.
// ---------------------------------------------------------------------------
__global__ __launch_bounds__(512, 4) void gather_kernel(const u16* __restrict__ xwb,
                                                        u64* __restrict__ sorted,
                                                        const u32* __restrict__ gcursor,
                                                        float* __restrict__ accumA) {
    __shared__ u32 scoff[PSTRIDE];    // 22016 B: col byte offsets (col*128)
    __shared__ u16 sval[PSTRIDE];     // 11008 B: edge vals (bf16 bits)
    __shared__ u32 rhist[BROWS], roff[BROWS], rcur[BROWS], sc[BROWS];
    __shared__ float part[8];
    const int tid = threadIdx.x, wave = tid >> 6, lane = tid & 63;
    const int b = blockIdx.x;
    u64* gbase = sorted + (size_t)b * BSTRIDE;
    const int cnt = min((int)gcursor[b], BSTRIDE);

    if (tid < BROWS) rhist[tid] = 0;
    __syncthreads();

    u64 ent[9];                       // ceil(4608/512)
    int nloc = 0;
    for (int i = tid; i < cnt; i += 512) {
        u64 p = gbase[i];
        ent[nloc++] = p;
        atomicAdd(&rhist[(int)(p & 127u)], 1u);
    }
    __syncthreads();

    if (tid < BROWS) sc[tid] = (rhist[tid] + 7u) & ~7u;
    __syncthreads();
    for (int off = 1; off < BROWS; off <<= 1) {
        u32 x = (tid < BROWS && tid >= off) ? sc[tid - off] : 0;
        __syncthreads();
        if (tid < BROWS) sc[tid] += x;
        __syncthreads();
    }
    if (tid < BROWS) {
        const u32 r0 = sc[tid] - ((rhist[tid] + 7u) & ~7u);
        roff[tid] = r0;
        rcur[tid] = r0;
    }
    __syncthreads();

    for (int j = 0; j < nloc; ++j) {
        const u64 p = ent[j];
        const u32 pos = atomicAdd(&rcur[(int)(p & 127u)], 1u);
        scoff[pos] = (((u32)(p >> 17)) & 0x1FFFFu) << 7;
        sval[pos]  = (u16)(p >> 34);
    }
    __syncthreads();

    if (tid < BROWS) {
        const int e = roff[tid] + rhist[tid];
        const int pe = roff[tid] + (int)((rhist[tid] + 7u) & ~7u);
        for (int k = e; k < pe; ++k) { scoff[k] = 0u; sval[k] = 0; }
    }
    __syncthreads();

    u16* embp = (u16*)gbase;          // entries dead (staged in LDS)
    const int g = lane >> 3;          // edge slot within group of 8
    const int eoff = (lane & 7) * 16; // byte offset of this lane's 16 B chunk
    const int g0 = g & 1, g1 = (g >> 1) & 1, g2 = (g >> 2) & 1;
    const int el = (lane & 7) * 8 + 4 * g0 + 2 * g1 + g2; // final element
    const char* xwc = (const char*)xwb;
    float wd = 0.f;

#define FMA8(X, V)                                         \
    acc[0] += (V) * __uint_as_float((X).x << 16);          \
    acc[1] += (V) * __uint_as_float((X).x & 0xFFFF0000u);  \
    acc[2] += (V) * __uint_as_float((X).y << 16);          \
    acc[3] += (V) * __uint_as_float((X).y & 0xFFFF0000u);  \
    acc[4] += (V) * __uint_as_float((X).z << 16);          \
    acc[5] += (V) * __uint_as_float((X).z & 0xFFFF0000u);  \
    acc[6] += (V) * __uint_as_float((X).w << 16);          \
    acc[7] += (V) * __uint_as_float((X).w & 0xFFFF0000u);

    for (int rr = 0; rr < 16; ++rr) {
        const int r = wave * 16 + rr;
        const int n8 = (int)((rhist[r] + 7u) & ~7u);
        const int base = (int)roff[r];
        float acc[8] = {0.f, 0.f, 0.f, 0.f, 0.f, 0.f, 0.f, 0.f};

        int j = 0;
        for (; j + 16 <= n8; j += 16) {
            const int i0 = base + j + g;
            const u32 c0 = scoff[i0];
            const u32 c1 = scoff[i0 + 8];
            const float v0 = bf2f(sval[i0]);
            const float v1 = bf2f(sval[i0 + 8]);
            const uint4 x0 = *(const uint4*)(xwc + (c0 + eoff));
            const uint4 x1 = *(const uint4*)(xwc + (c1 + eoff));
            FMA8(x0, v0)
            FMA8(x1, v1)
        }
        if (j < n8) {
            const int i0 = base + j + g;
            const u32 c0 = scoff[i0];
            const float v0 = bf2f(sval[i0]);
            const uint4 x0 = *(const uint4*)(xwc + (c0 + eoff));
            FMA8(x0, v0)
        }

        float k4[4];
#pragma unroll
        for (int i = 0; i < 4; ++i) {
            const float snd = g0 ? acc[i] : acc[i + 4];
            const float kp  = g0 ? acc[i + 4] : acc[i];
            k4[i] = kp + __shfl_xor(snd, 8, 64);
        }
        float k2[2];
#pragma unroll
        for (int i = 0; i < 2; ++i) {
            const float snd = g1 ? k4[i] : k4[i + 2];
            const float kp  = g1 ? k4[i + 2] : k4[i];
            k2[i] = kp + __shfl_xor(snd, 16, 64);
        }
        const float snd = g2 ? k2[0] : k2[1];
        const float kp  = g2 ? k2[1] : k2[0];
        const float s = kp + __shfl_xor(snd, 32, 64);

        const float t = tanhf(s);
        const float sq = wave_sum(t * t);
        const float rn = rsqrtf(fmaxf(sq, 1e-12f));
        if (b * BROWS + r < N_NODES)
            embp[r * EMB + el] = f2bf_rne(t * rn);
        wd += sq / fmaxf(sq, 1e-12f);   // 1 per non-empty row, 0 for empty
    }
#undef FMA8
    if (lane == 0) part[wave] = wd;
    __syncthreads();
    if (tid == 0) {
        float v = 0.f;
#pragma unroll
        for (int w = 0; w < 8; ++w) v += part[w];
        unsafeAtomicAdd(&accumA[b & 255], v);
    }
}

// ---------------------------------------------------------------------------
// 4) BPR: pure emb lookup. One wave per sample.
// ---------------------------------------------------------------------------
__device__ __forceinline__ float emb_ld(const u64* __restrict__ sorted, int row, int lane) {
    const u16* rp = (const u16*)(sorted + (size_t)(row >> 7) * BSTRIDE) + (row & 127) * EMB;
    return bf2f(rp[lane]);
}

__global__ __launch_bounds__(256) void bpr_kernel(const u64* __restrict__ sorted,
                                                  const int* __restrict__ idx1,
                                                  const int* __restrict__ idx2,
                                                  const int* __restrict__ nidx,
                                                  float* __restrict__ accumB) {
    const int wave = threadIdx.x >> 6, lane = threadIdx.x & 63;
    const int i = blockIdx.x * 4 + wave;
    float o1 = emb_ld(sorted, idx1[i], lane);
    float o2 = emb_ld(sorted, idx2[i], lane);
    float on = emb_ld(sorted, nidx[i], lane);
    float yui = wave_sum(o1 * o2);
    float yuj = wave_sum(o1 * on);
    if (lane == 0) {
        float x = yui - yuj;
        float li = (x > 0.f) ? log1pf(expf(-x)) : (-x + log1pf(expf(x)));
        unsafeAtomicAdd(&accumB[i & 255], li);
    }
}

// ---------------------------------------------------------------------------
// 5) finalize
// ---------------------------------------------------------------------------
__global__ __launch_bounds__(64) void finalize_kernel(const float* __restrict__ accumA,
                                                      const float* __restrict__ accumB,
                                                      float* __restrict__ out) {
    const int t = threadIdx.x;
    float wd = 0.f, bp = 0.f;
#pragma unroll
    for (int k = 0; k < 4; ++k) {
        wd += accumA[t + 64 * k];
        bp += accumB[t + 64 * k];
    }
    wd = wave_sum(wd);
    bp = wave_sum(bp);
    if (t == 0) out[0] = (bp + 1e-4f * 0.5f * wd) / (float)BATCH;
}

extern "C" void kernel_launch(void* const* d_in, const int* in_sizes, int n_in,
                              void* d_out, int out_size, void* d_ws, size_t ws_size,
                              hipStream_t stream) {
    const float* feats = (const float*)d_in[0];
    const float* W     = (const float*)d_in[1];
    const int*   erow  = (const int*)d_in[2];
    const int*   ecol  = (const int*)d_in[3];
    const float* eval  = (const float*)d_in[4];
    const int*   idx1  = (const int*)d_in[5];
    const int*   idx2  = (const int*)d_in[6];
    const int*   nidx  = (const int*)d_in[7];
    float* out = (float*)d_out;

    // workspace layout (~41.8 MB)
    u16*   xwb     = (u16*)d_ws;                               // 12.8 MB
    u64*   sorted  = (u64*)(xwb + (size_t)N_NODES * EMB);      // 782*4608*8 = 28.8 MB
    u32*   gcursor = (u32*)(sorted + (size_t)NBUCK * BSTRIDE); // 1024 u32
    float* accumA  = (float*)(gcursor + 1024);                 // 256
    float* accumB  = accumA + 256;                             // 256
    u16*   wpack   = (u16*)(accumB + 256);                     // 32 KB

    hipMemsetAsync(gcursor, 0, (1024 + 512) * sizeof(u32), stream);

    wpack_kernel<<<8, 256, 0, stream>>>(W, wpack);
    mfma_gemm_kernel<<<(MWAVES + 3) / 4, 256, 0, stream>>>(feats, wpack, xwb);
    passA_kernel<<<NPA, 1024, 0, stream>>>(erow, ecol, eval, gcursor, sorted);
    gather_kernel<<<NBUCK, 512, 0, stream>>>(xwb, sorted, gcursor, accumA);
    bpr_kernel<<<BATCH / 4, 256, 0, stream>>>(sorted, idx1, idx2, nidx, accumB);
    finalize_kernel<<<1, 64, 0, stream>>>(accumA, accumB, out);
}